// Round 5
// baseline (1275.619 us; speedup 1.0000x reference)
//
#include <hip/hip_runtime.h>
#include <math.h>

// Shapes: B=2, D=64, L=512, H=1024
// Phase 1 (proj): 256 blocks x 1024 threads (1 block/CU), block (bd=blk>>1, half=blk&1)
//   computes pX[bd, h-half] with 8 l-parity groups + 2-stage LDS tree combine.
// Phase 2 (recur): ONLY blocks 0..63 continue (16 waves each, 1 row/wave = 1024 rows);
//   blocks 64..255 exit after posting their phase-1 flag.
//   Sync = 4-RT distributed chain: state stores -> __syncthreads (vmcnt drain) ->
//   flag store -> every active block's wave 0 self-detects over the 64 flags
//   (ONE load/lane/round, 4 cache lines x 64 pollers — r3's contention / 16) -> state load.
//   No aggregator, no release broadcast (r0/r3/r4 evidence: cost = chainRTs x RT + contention).
//   LN affine folded into register-resident weight rows; per-wave stats (no red[] exchange);
//   own-row c/h register-resident.
//
// ws layout (floats):
//   [0,256)        flags (uint, 1/block; phase2 uses [0,64))   (pad to 320)
//   [320, 4416)    stC (2 parities x 2 x 1024)
//   [4416, 8512)   stH
//   [8512, 139584) pF   [139584, 270656) pI   [270656, 401728) pO
// memset: first 8512 floats (34 KB) only.

#define NACT 64

__device__ __forceinline__ float sigf(float x)   { return 1.0f / (1.0f + __expf(-x)); }
__device__ __forceinline__ float geluf(float x)  { return 0.5f * x * (1.0f + erff(x * 0.70710678118654752f)); }
__device__ __forceinline__ float clampf(float x, float lo, float hi) { return fminf(fmaxf(x, lo), hi); }

__device__ __forceinline__ void astf(float* p, float v) {
    __hip_atomic_store(p, v, __ATOMIC_RELAXED, __HIP_MEMORY_SCOPE_AGENT);
}
__device__ __forceinline__ float aldf(const float* p) {
    return __hip_atomic_load(p, __ATOMIC_RELAXED, __HIP_MEMORY_SCOPE_AGENT);
}
__device__ __forceinline__ void astu(unsigned* p, unsigned v) {
    __hip_atomic_store(p, v, __ATOMIC_RELAXED, __HIP_MEMORY_SCOPE_AGENT);
}
__device__ __forceinline__ unsigned aldu(const unsigned* p) {
    return __hip_atomic_load(p, __ATOMIC_RELAXED, __HIP_MEMORY_SCOPE_AGENT);
}

__global__ __launch_bounds__(1024, 1) void fused_kernel(
    const float* __restrict__ trans, const int* __restrict__ mask,
    const float* __restrict__ Wf, const float* __restrict__ bf,
    const float* __restrict__ Wi, const float* __restrict__ bi,
    const float* __restrict__ Wg, const float* __restrict__ bg,
    const float* __restrict__ Wo, const float* __restrict__ bo,
    const float* __restrict__ Wp, const float* __restrict__ bp,
    const float* __restrict__ tF, const float* __restrict__ tI, const float* __restrict__ tO,
    const float* __restrict__ c_gamma, const float* __restrict__ c_beta,
    const float* __restrict__ h_gamma, const float* __restrict__ h_beta,
    float* __restrict__ ws, float* __restrict__ out)
{
    const int t    = threadIdx.x;
    const int lane = t & 63;
    const int wv   = t >> 6;          // 0..15
    const int blk  = blockIdx.x;
    const bool act = (blk < NACT);
    const int hrow = (blk << 4) + wv; // valid only for act

    unsigned* flags = (unsigned*)ws;
    float* stC = ws + 320;
    float* stH = ws + 4416;
    float* pF  = ws + 8512;
    float* pI  = pF + 131072;
    float* pO  = pI + 131072;

    __shared__ float smem[2][4][1024];           // 8192 floats, re-carved per phase
    float* sbase = &smem[0][0][0];
    float4* cmb4 = (float4*)sbase;               // phase1: [g'(<=3)][proj][128 slots] -> 1536 f4
    float* sF = sbase + 6144;                    // phase1 tables: 512 each
    float* sI = sbase + 6656;
    float* sO = sbase + 7168;

    // ---- register-resident weight rows (active blocks only; issued early) ----
    float4 wfr[4], wir[4], wgr[4], wor[4], wpr[4];
    float bfv = 0.f, biv = 0.f, bgv = 0.f, bov = 0.f, bpv = 0.f;
    if (act) {
        const float4* rf = (const float4*)(Wf + (size_t)hrow * 1024);
        const float4* ri = (const float4*)(Wi + (size_t)hrow * 1024);
        const float4* rg = (const float4*)(Wg + (size_t)hrow * 1024);
        const float4* ro = (const float4*)(Wo + (size_t)hrow * 1024);
        const float4* rp = (const float4*)(Wp + (size_t)hrow * 1024);
        #pragma unroll
        for (int q = 0; q < 4; ++q) {
            const int k4 = lane + 64 * q;
            wfr[q] = rf[k4]; wir[q] = ri[k4]; wgr[q] = rg[k4];
            wor[q] = ro[k4]; wpr[q] = rp[k4];
        }
        bfv = bf[hrow]; biv = bi[hrow]; bgv = bg[hrow]; bov = bo[hrow]; bpv = bp[hrow];
    }

    // ================= Phase 1: projections (all 256 blocks) =================
    {
        if (t < 512) { sF[t] = tF[t]; sI[t] = tI[t]; sO[t] = tO[t]; }
        __syncthreads();

        const int bd = blk >> 1;
        const int h0 = (blk & 1) * 512;
        const int s  = t & 127;          // float4 slot within the 512-wide half
        const int g  = t >> 7;           // l-parity group 0..7
        const float4* tr = (const float4*)trans + (size_t)bd * 512 * 256 + (h0 >> 2) + s;

        float4 aF = make_float4(0.f,0.f,0.f,0.f);
        float4 aI = make_float4(0.f,0.f,0.f,0.f);
        float4 aO = make_float4(0.f,0.f,0.f,0.f);
        #pragma unroll 8
        for (int li = 0; li < 64; ++li) {
            const int l = g + 8 * li;
            float4 v = tr[(size_t)l * 256];
            const float wf = sF[l], wi = sI[l], wo = sO[l];
            aF.x = fmaf(v.x, wf, aF.x); aF.y = fmaf(v.y, wf, aF.y);
            aF.z = fmaf(v.z, wf, aF.z); aF.w = fmaf(v.w, wf, aF.w);
            aI.x = fmaf(v.x, wi, aI.x); aI.y = fmaf(v.y, wi, aI.y);
            aI.z = fmaf(v.z, wi, aI.z); aI.w = fmaf(v.w, wi, aI.w);
            aO.x = fmaf(v.x, wo, aO.x); aO.y = fmaf(v.y, wo, aO.y);
            aO.z = fmaf(v.z, wo, aO.z); aO.w = fmaf(v.w, wo, aO.w);
        }
        // stage A: groups 4..7 park partials; groups 0..3 absorb
        if (g >= 4) {
            const int gp = g - 4;
            cmb4[(gp * 3 + 0) * 128 + s] = aF;
            cmb4[(gp * 3 + 1) * 128 + s] = aI;
            cmb4[(gp * 3 + 2) * 128 + s] = aO;
        }
        __syncthreads();
        if (g < 4) {
            const float4 bF = cmb4[(g * 3 + 0) * 128 + s];
            const float4 bI = cmb4[(g * 3 + 1) * 128 + s];
            const float4 bO = cmb4[(g * 3 + 2) * 128 + s];
            aF.x += bF.x; aF.y += bF.y; aF.z += bF.z; aF.w += bF.w;
            aI.x += bI.x; aI.y += bI.y; aI.z += bI.z; aI.w += bI.w;
            aO.x += bO.x; aO.y += bO.y; aO.z += bO.z; aO.w += bO.w;
        }
        __syncthreads();
        // stage B: groups 1..3 park; group 0 absorbs and stores
        if (g >= 1 && g < 4) {
            const int gp = g - 1;
            cmb4[(gp * 3 + 0) * 128 + s] = aF;
            cmb4[(gp * 3 + 1) * 128 + s] = aI;
            cmb4[(gp * 3 + 2) * 128 + s] = aO;
        }
        __syncthreads();
        if (g == 0) {
            #pragma unroll
            for (int gp = 0; gp < 3; ++gp) {
                const float4 bF = cmb4[(gp * 3 + 0) * 128 + s];
                const float4 bI = cmb4[(gp * 3 + 1) * 128 + s];
                const float4 bO = cmb4[(gp * 3 + 2) * 128 + s];
                aF.x += bF.x; aF.y += bF.y; aF.z += bF.z; aF.w += bF.w;
                aI.x += bI.x; aI.y += bI.y; aI.z += bI.z; aI.w += bI.w;
                aO.x += bO.x; aO.y += bO.y; aO.z += bO.z; aO.w += bO.w;
            }
            const int base = bd * 1024 + h0 + 4 * s;
            astf(&pF[base+0], aF.x); astf(&pF[base+1], aF.y);
            astf(&pF[base+2], aF.z); astf(&pF[base+3], aF.w);
            astf(&pI[base+0], aI.x); astf(&pI[base+1], aI.y);
            astf(&pI[base+2], aI.z); astf(&pI[base+3], aI.w);
            astf(&pO[base+0], aO.x); astf(&pO[base+1], aO.y);
            astf(&pO[base+2], aO.z); astf(&pO[base+3], aO.w);
        }
    }
    __syncthreads();                     // drain proj stores (vmcnt(0) before s_barrier)
    if (t == 0) astu(&flags[blk], 1u);
    if (!act) return;                    // blocks 64..255 done

    // ---- fold LN affine into weights; per-row scalars (overlaps others' proj) ----
    float sfv, siv, sgv, sov, spv, bfb, bib, bgb, bob, bpb;
    {
        float4 gh4[4], bh4[4], gc4[4], bc4[4];
        const float4* Gh = (const float4*)h_gamma;
        const float4* Bh = (const float4*)h_beta;
        const float4* Gc = (const float4*)c_gamma;
        const float4* Bc = (const float4*)c_beta;
        #pragma unroll
        for (int q = 0; q < 4; ++q) {
            const int k4 = lane + 64 * q;
            gh4[q] = Gh[k4]; bh4[q] = Bh[k4]; gc4[q] = Gc[k4]; bc4[q] = Bc[k4];
        }
        bfb = bib = bgb = bob = bpb = 0.f;
        #pragma unroll
        for (int q = 0; q < 4; ++q) {
            bfb += wfr[q].x*bh4[q].x + wfr[q].y*bh4[q].y + wfr[q].z*bh4[q].z + wfr[q].w*bh4[q].w;
            bib += wir[q].x*bh4[q].x + wir[q].y*bh4[q].y + wir[q].z*bh4[q].z + wir[q].w*bh4[q].w;
            bgb += wgr[q].x*bh4[q].x + wgr[q].y*bh4[q].y + wgr[q].z*bh4[q].z + wgr[q].w*bh4[q].w;
            bob += wor[q].x*bh4[q].x + wor[q].y*bh4[q].y + wor[q].z*bh4[q].z + wor[q].w*bh4[q].w;
            bpb += wpr[q].x*bc4[q].x + wpr[q].y*bc4[q].y + wpr[q].z*bc4[q].z + wpr[q].w*bc4[q].w;
        }
        #pragma unroll
        for (int q = 0; q < 4; ++q) {
            wfr[q].x *= gh4[q].x; wfr[q].y *= gh4[q].y; wfr[q].z *= gh4[q].z; wfr[q].w *= gh4[q].w;
            wir[q].x *= gh4[q].x; wir[q].y *= gh4[q].y; wir[q].z *= gh4[q].z; wir[q].w *= gh4[q].w;
            wgr[q].x *= gh4[q].x; wgr[q].y *= gh4[q].y; wgr[q].z *= gh4[q].z; wgr[q].w *= gh4[q].w;
            wor[q].x *= gh4[q].x; wor[q].y *= gh4[q].y; wor[q].z *= gh4[q].z; wor[q].w *= gh4[q].w;
            wpr[q].x *= gc4[q].x; wpr[q].y *= gc4[q].y; wpr[q].z *= gc4[q].z; wpr[q].w *= gc4[q].w;
        }
        sfv = siv = sgv = sov = spv = 0.f;
        #pragma unroll
        for (int q = 0; q < 4; ++q) {
            sfv += wfr[q].x + wfr[q].y + wfr[q].z + wfr[q].w;
            siv += wir[q].x + wir[q].y + wir[q].z + wir[q].w;
            sgv += wgr[q].x + wgr[q].y + wgr[q].z + wgr[q].w;
            sov += wor[q].x + wor[q].y + wor[q].z + wor[q].w;
            spv += wpr[q].x + wpr[q].y + wpr[q].z + wpr[q].w;
        }
        #pragma unroll
        for (int off = 32; off; off >>= 1) {
            sfv += __shfl_xor(sfv, off); siv += __shfl_xor(siv, off);
            sgv += __shfl_xor(sgv, off); sov += __shfl_xor(sov, off);
            spv += __shfl_xor(spv, off);
            bfb += __shfl_xor(bfb, off); bib += __shfl_xor(bib, off);
            bgb += __shfl_xor(bgb, off); bob += __shfl_xor(bob, off);
            bpb += __shfl_xor(bpb, off);
        }
    }

    // ---- phase-1 completion wait over ALL 256 flags (before first proj prefetch) ----
    if (wv == 0) {
        for (;;) {
            const unsigned a0 = aldu(&flags[lane]);
            const unsigned a1 = aldu(&flags[lane + 64]);
            const unsigned a2 = aldu(&flags[lane + 128]);
            const unsigned a3 = aldu(&flags[lane + 192]);
            const int ok = (a0 >= 1u) && (a1 >= 1u) && (a2 >= 1u) && (a3 >= 1u);
            if (__all(ok)) break;
            __builtin_amdgcn_s_sleep(1);
        }
    }
    __syncthreads();

    // ================= Phase 2: recurrence (blocks 0..63, 16 waves) =================
    float c_prev = 0.f, h_prev = 0.f;    // lane<2: own row's state, register-resident

    for (int d = 0; d < 64; ++d) {
        const int par = d & 1;
        const float* cc = stC + par * 2048;
        const float* hc = stH + par * 2048;
        float* cn = stC + (par ^ 1) * 2048;
        float* hn = stH + (par ^ 1) * 2048;
        float (*sm)[1024] = smem[par];

        // prefetch this step's projection scalars + mask (latency hides under poll)
        float pfv = 0.f, piv = 0.f, pov = 0.f;
        int mv = 1;
        if (lane < 2) {
            const int pidx = (lane * 64 + d) * 1024 + hrow;
            pfv = aldf(&pF[pidx]); piv = aldf(&pI[pidx]); pov = aldf(&pO[pidx]);
            mv = mask[lane * 64 + d];
        }

        // ---- distributed self-detect over the 64 active flags (1 load/lane/round) ----
        if (wv == 0) {
            const unsigned tgt = (unsigned)(d + 1);
            for (;;) {
                const unsigned a0 = aldu(&flags[lane]);
                if (__all(a0 >= tgt)) break;
                __builtin_amdgcn_s_sleep(1);
            }
        }
        __syncthreads();

        // ---- cooperative state read (agent scope) -> raw into smem (1 elem/thread/array) ----
        const float lh0 = aldf(hc + t);
        const float lh1 = aldf(hc + 1024 + t);
        const float lc0 = aldf(cc + t);
        const float lc1 = aldf(cc + 1024 + t);
        sm[0][t] = lh0; sm[1][t] = lh1; sm[2][t] = lc0; sm[3][t] = lc1;
        __syncthreads();

        // ---- 10 dot products on RAW state + per-wave LN stats ----
        float zf0=0,zf1=0,zi0=0,zi1=0,zg0=0,zg1=0,zo0=0,zo1=0,zp0=0,zp1=0;
        float sH0=0,qH0=0,sH1=0,qH1=0,sC0=0,qC0=0,sC1=0,qC1=0;
        #pragma unroll
        for (int q = 0; q < 4; ++q) {
            const int k4 = lane + 64 * q;
            const float4 n0 = ((const float4*)sm[0])[k4];
            const float4 n1 = ((const float4*)sm[1])[k4];
            const float4 m0 = ((const float4*)sm[2])[k4];
            const float4 m1 = ((const float4*)sm[3])[k4];
            zf0 += wfr[q].x*n0.x + wfr[q].y*n0.y + wfr[q].z*n0.z + wfr[q].w*n0.w;
            zf1 += wfr[q].x*n1.x + wfr[q].y*n1.y + wfr[q].z*n1.z + wfr[q].w*n1.w;
            zi0 += wir[q].x*n0.x + wir[q].y*n0.y + wir[q].z*n0.z + wir[q].w*n0.w;
            zi1 += wir[q].x*n1.x + wir[q].y*n1.y + wir[q].z*n1.z + wir[q].w*n1.w;
            zg0 += wgr[q].x*n0.x + wgr[q].y*n0.y + wgr[q].z*n0.z + wgr[q].w*n0.w;
            zg1 += wgr[q].x*n1.x + wgr[q].y*n1.y + wgr[q].z*n1.z + wgr[q].w*n1.w;
            zo0 += wor[q].x*n0.x + wor[q].y*n0.y + wor[q].z*n0.z + wor[q].w*n0.w;
            zo1 += wor[q].x*n1.x + wor[q].y*n1.y + wor[q].z*n1.z + wor[q].w*n1.w;
            zp0 += wpr[q].x*m0.x + wpr[q].y*m0.y + wpr[q].z*m0.z + wpr[q].w*m0.w;
            zp1 += wpr[q].x*m1.x + wpr[q].y*m1.y + wpr[q].z*m1.z + wpr[q].w*m1.w;
            sH0 += n0.x + n0.y + n0.z + n0.w;
            qH0 += n0.x*n0.x + n0.y*n0.y + n0.z*n0.z + n0.w*n0.w;
            sH1 += n1.x + n1.y + n1.z + n1.w;
            qH1 += n1.x*n1.x + n1.y*n1.y + n1.z*n1.z + n1.w*n1.w;
            sC0 += m0.x + m0.y + m0.z + m0.w;
            qC0 += m0.x*m0.x + m0.y*m0.y + m0.z*m0.z + m0.w*m0.w;
            sC1 += m1.x + m1.y + m1.z + m1.w;
            qC1 += m1.x*m1.x + m1.y*m1.y + m1.z*m1.z + m1.w*m1.w;
        }
        #pragma unroll
        for (int off = 32; off; off >>= 1) {
            zf0 += __shfl_xor(zf0, off); zf1 += __shfl_xor(zf1, off);
            zi0 += __shfl_xor(zi0, off); zi1 += __shfl_xor(zi1, off);
            zg0 += __shfl_xor(zg0, off); zg1 += __shfl_xor(zg1, off);
            zo0 += __shfl_xor(zo0, off); zo1 += __shfl_xor(zo1, off);
            zp0 += __shfl_xor(zp0, off); zp1 += __shfl_xor(zp1, off);
            sH0 += __shfl_xor(sH0, off); qH0 += __shfl_xor(qH0, off);
            sH1 += __shfl_xor(sH1, off); qH1 += __shfl_xor(qH1, off);
            sC0 += __shfl_xor(sC0, off); qC0 += __shfl_xor(qC0, off);
            sC1 += __shfl_xor(sC1, off); qC1 += __shfl_xor(qC1, off);
        }

        // ---- finalize z (affine correction) + gates: lane 0 -> b=0, lane 1 -> b=1 ----
        if (lane < 2) {
            const int b = lane;
            const float inv = 1.0f / 1024.0f;
            const float mh = (b ? sH1 : sH0) * inv;
            const float qh = (b ? qH1 : qH0) * inv;
            const float rh = rsqrtf(qh - mh * mh + 1e-5f);
            const float mc = (b ? sC1 : sC0) * inv;
            const float qc = (b ? qC1 : qC0) * inv;
            const float rc = rsqrtf(qc - mc * mc + 1e-5f);
            const float zf = rh * ((b ? zf1 : zf0) - mh * sfv) + bfb;
            const float zi = rh * ((b ? zi1 : zi0) - mh * siv) + bib;
            const float zg = rh * ((b ? zg1 : zg0) - mh * sgv) + bgb;
            const float zo = rh * ((b ? zo1 : zo0) - mh * sov) + bob;
            const float zp = rc * ((b ? zp1 : zp0) - mc * spv) + bpb;
            const float f  = sigf(clampf(zf + bfv, -8.f, 8.f) + pfv);
            const float ig = sigf(clampf(zi + biv, -8.f, 8.f) + piv);
            const float g  = clampf(geluf(zg + bgv) + piv, -8.f, 8.f);
            const float o  = sigf(clampf(zo + bov, -8.f, 8.f) + pov);
            const float hp = clampf(geluf(zp + bpv), -8.f, 8.f);
            float c2 = c_prev * f + ig * g;
            float h2 = o * hp;
            if (mv == 0) { c2 = c_prev; h2 = h_prev; }
            c2 = clampf(c2, -10.f, 10.f);
            h2 = clampf(h2, -10.f, 10.f);
            c_prev = c2; h_prev = h2;
            if (d == 63) {
                out[b * 1024 + hrow] = h2;
            } else {
                astf(cn + b * 1024 + hrow, c2);
                astf(hn + b * 1024 + hrow, h2);
            }
        }

        if (d == 63) break;
        __syncthreads();                         // drain state stores (vmcnt(0) before s_barrier)
        if (t == 0) astu(&flags[blk], (unsigned)(d + 2));
    }
}

extern "C" void kernel_launch(void* const* d_in, const int* in_sizes, int n_in,
                              void* d_out, int out_size, void* d_ws, size_t ws_size,
                              hipStream_t stream)
{
    const float* trans = (const float*)d_in[0];
    const int*   mask  = (const int*)d_in[1];
    const float* Wf = (const float*)d_in[2];  const float* bf = (const float*)d_in[3];
    const float* Wi = (const float*)d_in[4];  const float* bi = (const float*)d_in[5];
    const float* Wg = (const float*)d_in[6];  const float* bg = (const float*)d_in[7];
    const float* Wo = (const float*)d_in[8];  const float* bo = (const float*)d_in[9];
    const float* Wp = (const float*)d_in[10]; const float* bp = (const float*)d_in[11];
    const float* tF = (const float*)d_in[12];
    const float* tI = (const float*)d_in[13];
    const float* tO = (const float*)d_in[14];
    const float* c_gamma = (const float*)d_in[15];
    const float* c_beta  = (const float*)d_in[16];
    const float* h_gamma = (const float*)d_in[17];
    const float* h_beta  = (const float*)d_in[18];

    float* ws  = (float*)d_ws;
    float* out = (float*)d_out;

    // zero flags + initial c/h state only (34 KB)
    hipMemsetAsync(d_ws, 0, 8512u * sizeof(float), stream);

    void* args[] = { (void*)&trans, (void*)&mask,
                     (void*)&Wf, (void*)&bf, (void*)&Wi, (void*)&bi,
                     (void*)&Wg, (void*)&bg, (void*)&Wo, (void*)&bo,
                     (void*)&Wp, (void*)&bp,
                     (void*)&tF, (void*)&tI, (void*)&tO,
                     (void*)&c_gamma, (void*)&c_beta, (void*)&h_gamma, (void*)&h_beta,
                     (void*)&ws, (void*)&out };
    hipLaunchCooperativeKernel((void*)fused_kernel, dim3(256), dim3(1024), args, 0, stream);
}